// Round 1
// baseline (1865.146 us; speedup 1.0000x reference)
//
#include <hip/hip_runtime.h>
#include <hip/hip_bf16.h>
#include <math.h>

#define BB 2
#define LL 2048
#define DD 768
#define DN 1536
#define NS 16
#define DTR 48
#define MM (BB*LL)   // 4096

__device__ __forceinline__ float siluf(float x) {
    return x * (1.f / (1.f + expf(-x)));
}
__device__ __forceinline__ float softplusf(float x) {
    return (x > 20.f) ? x : log1pf(expf(x));
}

// ---------------- Kernel 1: LayerNorm + FiLM ----------------
__global__ void ln_film_kernel(const float* __restrict__ x,
                               const float* __restrict__ gamma,
                               const float* __restrict__ beta,
                               const float* __restrict__ ln_g,
                               const float* __restrict__ ln_b,
                               float* __restrict__ xn)
{
    int r = blockIdx.x;            // 0..M-1 (b*L + l)
    int b = r / LL;
    const float* xr = x + (size_t)r * DD;
    int tid = threadIdx.x;

    float v[3];
    float s = 0.f, ss = 0.f;
#pragma unroll
    for (int j = 0; j < 3; ++j) {
        v[j] = xr[tid + j * 256];
        s += v[j];
        ss += v[j] * v[j];
    }
    // wave reduce (64 lanes)
#pragma unroll
    for (int o = 32; o >= 1; o >>= 1) {
        s  += __shfl_xor(s, o, 64);
        ss += __shfl_xor(ss, o, 64);
    }
    __shared__ float ws_s[4], ws_ss[4];
    int wave = tid >> 6;
    if ((tid & 63) == 0) { ws_s[wave] = s; ws_ss[wave] = ss; }
    __syncthreads();
    float tot_s  = ws_s[0] + ws_s[1] + ws_s[2] + ws_s[3];
    float tot_ss = ws_ss[0] + ws_ss[1] + ws_ss[2] + ws_ss[3];
    float mu  = tot_s * (1.f / DD);
    float var = tot_ss * (1.f / DD) - mu * mu;
    float inv = rsqrtf(var + 1e-5f);

#pragma unroll
    for (int j = 0; j < 3; ++j) {
        int i = tid + j * 256;
        float xv = (v[j] - mu) * inv * ln_g[i] + ln_b[i];
        xv = xv * gamma[b * DD + i] + beta[b * DD + i];
        xn[(size_t)r * DD + i] = xv;
    }
}

// ---------------- Generic GEMM: C[M,N] = A[M,K] * W[N,K]^T ----------------
// EPI 0: plain store; EPI 1: +bias then softplus; EPI 2: +resid
template<int EPI>
__global__ void gemm_tn_kernel(const float* __restrict__ A, int lda,
                               const float* __restrict__ W,
                               float* __restrict__ C, int ldc,
                               int M, int N, int K,
                               const float* __restrict__ bias,
                               const float* __restrict__ resid)
{
    __shared__ __align__(16) float As[16][68];
    __shared__ __align__(16) float Ws[16][68];
    int m0 = blockIdx.y * 64;
    int n0 = blockIdx.x * 64;
    int tid = threadIdx.x;
    int tx = tid & 15;
    int ty = tid >> 4;
    int lk = tid & 15;   // k within tile
    int lm = tid >> 4;   // row within tile (step 16)

    float acc[4][4] = {};

    for (int k0 = 0; k0 < K; k0 += 16) {
#pragma unroll
        for (int j = 0; j < 4; ++j) {
            int m = m0 + lm + j * 16;
            As[lk][lm + j * 16] = (m < M) ? A[(size_t)m * lda + (k0 + lk)] : 0.f;
        }
#pragma unroll
        for (int j = 0; j < 4; ++j) {
            int n = n0 + lm + j * 16;
            Ws[lk][lm + j * 16] = (n < N) ? W[(size_t)n * K + (k0 + lk)] : 0.f;
        }
        __syncthreads();
#pragma unroll
        for (int kk = 0; kk < 16; ++kk) {
            float a[4], w[4];
#pragma unroll
            for (int i = 0; i < 4; ++i) a[i] = As[kk][ty * 4 + i];
#pragma unroll
            for (int i = 0; i < 4; ++i) w[i] = Ws[kk][tx * 4 + i];
#pragma unroll
            for (int i = 0; i < 4; ++i)
#pragma unroll
                for (int j = 0; j < 4; ++j)
                    acc[i][j] = fmaf(a[i], w[j], acc[i][j]);
        }
        __syncthreads();
    }

#pragma unroll
    for (int i = 0; i < 4; ++i) {
        int m = m0 + ty * 4 + i;
        if (m >= M) continue;
#pragma unroll
        for (int j = 0; j < 4; ++j) {
            int n = n0 + tx * 4 + j;
            if (n >= N) continue;
            float v = acc[i][j];
            if (EPI == 1) v = softplusf(v + bias[n]);
            if (EPI == 2) v += resid[(size_t)m * ldc + n];
            C[(size_t)m * ldc + n] = v;
        }
    }
}

// ---------------- Kernel 3: causal depthwise conv + SiLU ----------------
__global__ void conv_silu_kernel(const float* __restrict__ xz,  // [M, 2*DN], x part at [:, :DN]
                                 const float* __restrict__ cw,  // [DN,4]
                                 const float* __restrict__ cb,  // [DN]
                                 float* __restrict__ xin)       // [M, DN]
{
    int idx = blockIdx.x * blockDim.x + threadIdx.x;
    if (idx >= MM * DN) return;
    int dn = idx % DN;
    int r  = idx / DN;       // b*L + l
    int l  = r % LL;
    float acc = cb[dn];
#pragma unroll
    for (int k = 0; k < 4; ++k) {
        int lt = l - 3 + k;
        if (lt >= 0)
            acc = fmaf(xz[(size_t)(r - 3 + k) * (2 * DN) + dn], cw[dn * 4 + k], acc);
    }
    xin[idx] = siluf(acc);
}

// ---------------- Kernel 5: selective scan ----------------
// 16 lanes per channel (one per state); 16 channels per 256-thread block.
__global__ void scan_kernel(const float* __restrict__ dt,    // [B,L,DN]
                            const float* __restrict__ xdbl,  // [B,L,80]
                            const float* __restrict__ xin,   // [B,L,DN]
                            const float* __restrict__ A_log, // [DN,16]
                            float* __restrict__ ys)          // [B,L,DN]
{
    int tid = threadIdx.x;
    int lane_n = tid & 15;           // state index
    int grp = tid >> 4;              // 0..15
    int c = blockIdx.x * 16 + grp;   // 0..B*DN-1
    int b = c / DN;
    int dn = c % DN;

    float A = -expf(A_log[dn * NS + lane_n]);
    float h = 0.f;
    const float* dt_p = dt   + (size_t)b * LL * DN + dn;
    const float* u_p  = xin  + (size_t)b * LL * DN + dn;
    const float* B_p  = xdbl + (size_t)b * LL * 80 + DTR + lane_n;
    const float* C_p  = xdbl + (size_t)b * LL * 80 + DTR + NS + lane_n;
    float* y_p = ys + (size_t)b * LL * DN + dn;

    for (int t = 0; t < LL; ++t) {
        float dtv = dt_p[(size_t)t * DN];
        float u   = u_p[(size_t)t * DN];
        float Bv  = B_p[(size_t)t * 80];
        float Cv  = C_p[(size_t)t * 80];
        float dA  = expf(dtv * A);
        h = fmaf(h, dA, dtv * Bv * u);
        float p = h * Cv;
        p += __shfl_xor(p, 1, 64);
        p += __shfl_xor(p, 2, 64);
        p += __shfl_xor(p, 4, 64);
        p += __shfl_xor(p, 8, 64);
        if (lane_n == 0) y_p[(size_t)t * DN] = p;
    }
}

// ---------------- Kernel 6a: gate y = (ys + Dp*xin) * silu(z) ----------------
__global__ void gate_kernel(float* __restrict__ ys,
                            const float* __restrict__ xin,
                            const float* __restrict__ xz,   // z at [:, DN:2DN]
                            const float* __restrict__ Dp)
{
    int idx = blockIdx.x * blockDim.x + threadIdx.x;
    if (idx >= MM * DN) return;
    int dn = idx % DN;
    int r  = idx / DN;
    float z = xz[(size_t)r * (2 * DN) + DN + dn];
    float y = ys[idx] + Dp[dn] * xin[idx];
    ys[idx] = y * siluf(z);
}

extern "C" void kernel_launch(void* const* d_in, const int* in_sizes, int n_in,
                              void* d_out, int out_size, void* d_ws, size_t ws_size,
                              hipStream_t stream) {
    const float* x         = (const float*)d_in[0];
    const float* gamma     = (const float*)d_in[1];
    const float* beta      = (const float*)d_in[2];
    const float* ln_g      = (const float*)d_in[3];
    const float* ln_b      = (const float*)d_in[4];
    const float* in_proj_w = (const float*)d_in[5];
    const float* conv_w    = (const float*)d_in[6];
    const float* conv_b    = (const float*)d_in[7];
    const float* x_proj_w  = (const float*)d_in[8];
    const float* dt_proj_w = (const float*)d_in[9];
    const float* dt_proj_b = (const float*)d_in[10];
    const float* A_log     = (const float*)d_in[11];
    const float* Dp        = (const float*)d_in[12];
    const float* out_proj_w= (const float*)d_in[13];
    float* out = (float*)d_out;

    float* xn   = (float*)d_ws;                  // M*D
    float* xz   = xn   + (size_t)MM * DD;        // M*2*DN
    float* xin  = xz   + (size_t)MM * 2 * DN;    // M*DN
    float* xdbl = xin  + (size_t)MM * DN;        // M*80
    float* dt   = xdbl + (size_t)MM * 80;        // M*DN
    float* ys   = dt   + (size_t)MM * DN;        // M*DN

    // 1. LN + FiLM
    ln_film_kernel<<<MM, 256, 0, stream>>>(x, gamma, beta, ln_g, ln_b, xn);

    // 2. xz = xn @ in_proj_w^T   [4096 x 3072]
    gemm_tn_kernel<0><<<dim3(3072/64, MM/64), 256, 0, stream>>>(
        xn, DD, in_proj_w, xz, 2*DN, MM, 2*DN, DD, nullptr, nullptr);

    // 3. conv + silu -> xin
    conv_silu_kernel<<<(MM*DN + 255)/256, 256, 0, stream>>>(xz, conv_w, conv_b, xin);

    // 4a. x_dbl = xin @ x_proj_w^T   [4096 x 80]
    gemm_tn_kernel<0><<<dim3(2, MM/64), 256, 0, stream>>>(
        xin, DN, x_proj_w, xdbl, 80, MM, 80, DN, nullptr, nullptr);

    // 4b. dt = softplus(x_dbl[:, :48] @ dt_proj_w^T + b)   [4096 x 1536]
    gemm_tn_kernel<1><<<dim3(DN/64, MM/64), 256, 0, stream>>>(
        xdbl, 80, dt_proj_w, dt, DN, MM, DN, DTR, dt_proj_b, nullptr);

    // 5. selective scan -> ys
    scan_kernel<<<(BB*DN)/16, 256, 0, stream>>>(dt, xdbl, xin, A_log, ys);

    // 6a. gate (in-place on ys)
    gate_kernel<<<(MM*DN + 255)/256, 256, 0, stream>>>(ys, xin, xz, Dp);

    // 6b. out = x + ys @ out_proj_w^T   [4096 x 768]
    gemm_tn_kernel<2><<<dim3(DD/64, MM/64), 256, 0, stream>>>(
        ys, DN, out_proj_w, out, DD, MM, DD, DN, nullptr, x);
}

// Round 3
// 1160.096 us; speedup vs baseline: 1.6078x; 1.6078x over previous
//
#include <hip/hip_runtime.h>
#include <hip/hip_bf16.h>
#include <math.h>

#define BB 2
#define LL 2048
#define DD 768
#define DN 1536
#define NS 16
#define DTR 48
#define MM (BB*LL)   // 4096
#define CHUNK 128
#define NCHUNK 16    // LL / CHUNK

__device__ __forceinline__ float siluf(float x) {
    return x * (1.f / (1.f + expf(-x)));
}
__device__ __forceinline__ float softplusf(float x) {
    return (x > 20.f) ? x : log1pf(expf(x));
}

// ---------------- Kernel 1: LayerNorm + FiLM ----------------
__global__ void ln_film_kernel(const float* __restrict__ x,
                               const float* __restrict__ gamma,
                               const float* __restrict__ beta,
                               const float* __restrict__ ln_g,
                               const float* __restrict__ ln_b,
                               float* __restrict__ xn)
{
    int r = blockIdx.x;            // 0..M-1 (b*L + l)
    int b = r / LL;
    const float* xr = x + (size_t)r * DD;
    int tid = threadIdx.x;

    float v[3];
    float s = 0.f, ss = 0.f;
#pragma unroll
    for (int j = 0; j < 3; ++j) {
        v[j] = xr[tid + j * 256];
        s += v[j];
        ss += v[j] * v[j];
    }
#pragma unroll
    for (int o = 32; o >= 1; o >>= 1) {
        s  += __shfl_xor(s, o, 64);
        ss += __shfl_xor(ss, o, 64);
    }
    __shared__ float ws_s[4], ws_ss[4];
    int wave = tid >> 6;
    if ((tid & 63) == 0) { ws_s[wave] = s; ws_ss[wave] = ss; }
    __syncthreads();
    float tot_s  = ws_s[0] + ws_s[1] + ws_s[2] + ws_s[3];
    float tot_ss = ws_ss[0] + ws_ss[1] + ws_ss[2] + ws_ss[3];
    float mu  = tot_s * (1.f / DD);
    float var = tot_ss * (1.f / DD) - mu * mu;
    float inv = rsqrtf(var + 1e-5f);

#pragma unroll
    for (int j = 0; j < 3; ++j) {
        int i = tid + j * 256;
        float xv = (v[j] - mu) * inv * ln_g[i] + ln_b[i];
        xv = xv * gamma[b * DD + i] + beta[b * DD + i];
        xn[(size_t)r * DD + i] = xv;
    }
}

// ---------------- Generic GEMM: C[M,N] = A[M,K] * W[N,K]^T ----------------
// EPI 0: plain store; EPI 1: +bias then softplus; EPI 2: +resid
template<int EPI>
__global__ void gemm_tn_kernel(const float* __restrict__ A, int lda,
                               const float* __restrict__ W,
                               float* __restrict__ C, int ldc,
                               int M, int N, int K,
                               const float* __restrict__ bias,
                               const float* __restrict__ resid)
{
    __shared__ __align__(16) float As[16][68];
    __shared__ __align__(16) float Ws[16][68];
    int m0 = blockIdx.y * 64;
    int n0 = blockIdx.x * 64;
    int tid = threadIdx.x;
    int tx = tid & 15;
    int ty = tid >> 4;
    int lk = tid & 15;   // k within tile
    int lm = tid >> 4;   // row within tile (step 16)

    float acc[4][4] = {};

    for (int k0 = 0; k0 < K; k0 += 16) {
#pragma unroll
        for (int j = 0; j < 4; ++j) {
            int m = m0 + lm + j * 16;
            As[lk][lm + j * 16] = (m < M) ? A[(size_t)m * lda + (k0 + lk)] : 0.f;
        }
#pragma unroll
        for (int j = 0; j < 4; ++j) {
            int n = n0 + lm + j * 16;
            Ws[lk][lm + j * 16] = (n < N) ? W[(size_t)n * K + (k0 + lk)] : 0.f;
        }
        __syncthreads();
#pragma unroll
        for (int kk = 0; kk < 16; ++kk) {
            float a[4], w[4];
#pragma unroll
            for (int i = 0; i < 4; ++i) a[i] = As[kk][ty * 4 + i];
#pragma unroll
            for (int i = 0; i < 4; ++i) w[i] = Ws[kk][tx * 4 + i];
#pragma unroll
            for (int i = 0; i < 4; ++i)
#pragma unroll
                for (int j = 0; j < 4; ++j)
                    acc[i][j] = fmaf(a[i], w[j], acc[i][j]);
        }
        __syncthreads();
    }

#pragma unroll
    for (int i = 0; i < 4; ++i) {
        int m = m0 + ty * 4 + i;
        if (m >= M) continue;
#pragma unroll
        for (int j = 0; j < 4; ++j) {
            int n = n0 + tx * 4 + j;
            if (n >= N) continue;
            float v = acc[i][j];
            if (EPI == 1) v = softplusf(v + bias[n]);
            if (EPI == 2) v += resid[(size_t)m * ldc + n];
            C[(size_t)m * ldc + n] = v;
        }
    }
}

// ---------------- Kernel 3: causal depthwise conv + SiLU ----------------
__global__ void conv_silu_kernel(const float* __restrict__ xz,  // [M, 2*DN], x part at [:, :DN]
                                 const float* __restrict__ cw,  // [DN,4]
                                 const float* __restrict__ cb,  // [DN]
                                 float* __restrict__ xin)       // [M, DN]
{
    int idx = blockIdx.x * blockDim.x + threadIdx.x;
    if (idx >= MM * DN) return;
    int dn = idx % DN;
    int r  = idx / DN;       // b*L + l
    int l  = r % LL;
    float acc = cb[dn];
#pragma unroll
    for (int k = 0; k < 4; ++k) {
        int lt = l - 3 + k;
        if (lt >= 0)
            acc = fmaf(xz[(size_t)(r - 3 + k) * (2 * DN) + dn], cw[dn * 4 + k], acc);
    }
    xin[idx] = siluf(acc);
}

// ---------------- Kernel 5: chunked parallel selective scan ----------------
// One block per (b, dn). 256 threads = 16 chunks x 16 state-lanes.
// Linear recurrence h[t] = dA[t]*h[t-1] + b[t]:
//  phase 1: each chunk scans 128 steps from 0, records (prod dA, h_final)
//  phase 2: each thread combines preceding chunk summaries -> entry state H0
//  phase 3: re-scan chunk from H0, emit y via intra-16 shfl reduce.
__global__ void scan_kernel(const float* __restrict__ dt,    // [B,L,DN]
                            const float* __restrict__ xdbl,  // [B,L,80]
                            const float* __restrict__ xin,   // [B,L,DN]
                            const float* __restrict__ A_log, // [DN,16]
                            float* __restrict__ ys)          // [B,L,DN]
{
    int c = blockIdx.x;              // 0..B*DN-1
    int b = c / DN;
    int dn = c % DN;
    int tid = threadIdx.x;
    int lane_n = tid & 15;           // state index
    int chunk  = tid >> 4;           // 0..15

    float A = -expf(A_log[dn * NS + lane_n]);

    const size_t base = (size_t)b * LL * DN + dn;
    const float* dt_p = dt  + base;
    const float* u_p  = xin + base;
    const float* B_p  = xdbl + (size_t)b * LL * 80 + DTR + lane_n;
    const float* C_p  = B_p + NS;
    float* y_p = ys + base;

    int t0 = chunk * CHUNK;

    // Phase 1: local scan from zero state
    float h = 0.f, aprod = 1.f;
    for (int t = t0; t < t0 + CHUNK; ++t) {
        float dtv = dt_p[(size_t)t * DN];
        float u   = u_p[(size_t)t * DN];
        float Bv  = B_p[(size_t)t * 80];
        float dA  = expf(dtv * A);
        h = fmaf(h, dA, dtv * Bv * u);
        aprod *= dA;
    }
    __shared__ float sh_h[NCHUNK][NS];
    __shared__ float sh_a[NCHUNK][NS];
    sh_h[chunk][lane_n] = h;
    sh_a[chunk][lane_n] = aprod;
    __syncthreads();

    // Phase 2: per-thread combine of preceding chunk summaries (<=15 iters)
    float H0 = 0.f;
    for (int cc = 0; cc < chunk; ++cc)
        H0 = fmaf(sh_a[cc][lane_n], H0, sh_h[cc][lane_n]);

    // Phase 3: re-scan with correct entry state, emit y
    h = H0;
    for (int t = t0; t < t0 + CHUNK; ++t) {
        float dtv = dt_p[(size_t)t * DN];
        float u   = u_p[(size_t)t * DN];
        float Bv  = B_p[(size_t)t * 80];
        float Cv  = C_p[(size_t)t * 80];
        float dA  = expf(dtv * A);
        h = fmaf(h, dA, dtv * Bv * u);
        float p = h * Cv;
        p += __shfl_xor(p, 1, 64);
        p += __shfl_xor(p, 2, 64);
        p += __shfl_xor(p, 4, 64);
        p += __shfl_xor(p, 8, 64);
        if (lane_n == 0) y_p[(size_t)t * DN] = p;
    }
}

// ---------------- Kernel 6a: gate y = (ys + Dp*xin) * silu(z) ----------------
__global__ void gate_kernel(float* __restrict__ ys,
                            const float* __restrict__ xin,
                            const float* __restrict__ xz,   // z at [:, DN:2DN]
                            const float* __restrict__ Dp)
{
    int idx = blockIdx.x * blockDim.x + threadIdx.x;
    if (idx >= MM * DN) return;
    int dn = idx % DN;
    int r  = idx / DN;
    float z = xz[(size_t)r * (2 * DN) + DN + dn];
    float y = ys[idx] + Dp[dn] * xin[idx];
    ys[idx] = y * siluf(z);
}

extern "C" void kernel_launch(void* const* d_in, const int* in_sizes, int n_in,
                              void* d_out, int out_size, void* d_ws, size_t ws_size,
                              hipStream_t stream) {
    const float* x         = (const float*)d_in[0];
    const float* gamma     = (const float*)d_in[1];
    const float* beta      = (const float*)d_in[2];
    const float* ln_g      = (const float*)d_in[3];
    const float* ln_b      = (const float*)d_in[4];
    const float* in_proj_w = (const float*)d_in[5];
    const float* conv_w    = (const float*)d_in[6];
    const float* conv_b    = (const float*)d_in[7];
    const float* x_proj_w  = (const float*)d_in[8];
    const float* dt_proj_w = (const float*)d_in[9];
    const float* dt_proj_b = (const float*)d_in[10];
    const float* A_log     = (const float*)d_in[11];
    const float* Dp        = (const float*)d_in[12];
    const float* out_proj_w= (const float*)d_in[13];
    float* out = (float*)d_out;

    float* xn   = (float*)d_ws;                  // M*D
    float* xz   = xn   + (size_t)MM * DD;        // M*2*DN
    float* xin  = xz   + (size_t)MM * 2 * DN;    // M*DN
    float* xdbl = xin  + (size_t)MM * DN;        // M*80
    float* dt   = xdbl + (size_t)MM * 80;        // M*DN
    float* ys   = dt   + (size_t)MM * DN;        // M*DN

    // 1. LN + FiLM
    ln_film_kernel<<<MM, 256, 0, stream>>>(x, gamma, beta, ln_g, ln_b, xn);

    // 2. xz = xn @ in_proj_w^T   [4096 x 3072]
    gemm_tn_kernel<0><<<dim3(3072/64, MM/64), 256, 0, stream>>>(
        xn, DD, in_proj_w, xz, 2*DN, MM, 2*DN, DD, nullptr, nullptr);

    // 3. conv + silu -> xin
    conv_silu_kernel<<<(MM*DN + 255)/256, 256, 0, stream>>>(xz, conv_w, conv_b, xin);

    // 4a. x_dbl = xin @ x_proj_w^T   [4096 x 80]
    gemm_tn_kernel<0><<<dim3(2, MM/64), 256, 0, stream>>>(
        xin, DN, x_proj_w, xdbl, 80, MM, 80, DN, nullptr, nullptr);

    // 4b. dt = softplus(x_dbl[:, :48] @ dt_proj_w^T + b)   [4096 x 1536]
    gemm_tn_kernel<1><<<dim3(DN/64, MM/64), 256, 0, stream>>>(
        xdbl, 80, dt_proj_w, dt, DN, MM, DN, DTR, dt_proj_b, nullptr);

    // 5. chunked parallel selective scan -> ys
    scan_kernel<<<BB*DN, 256, 0, stream>>>(dt, xdbl, xin, A_log, ys);

    // 6a. gate (in-place on ys)
    gate_kernel<<<(MM*DN + 255)/256, 256, 0, stream>>>(ys, xin, xz, Dp);

    // 6b. out = x + ys @ out_proj_w^T   [4096 x 768]
    gemm_tn_kernel<2><<<dim3(DD/64, MM/64), 256, 0, stream>>>(
        ys, DN, out_proj_w, out, DD, MM, DD, DN, nullptr, x);
}

// Round 4
// 707.992 us; speedup vs baseline: 2.6344x; 1.6386x over previous
//
#include <hip/hip_runtime.h>
#include <hip/hip_bf16.h>
#include <math.h>

#define BB 2
#define LL 2048
#define DD 768
#define DN 1536
#define NS 16
#define DTR 48
#define MM (BB*LL)   // 4096
#define CHUNK 128
#define NCHUNK 16    // LL / CHUNK

using frag8 = __attribute__((ext_vector_type(8))) short;   // 8 bf16 (4 VGPRs)
using f32x4 = __attribute__((ext_vector_type(4))) float;

__device__ __forceinline__ float siluf(float x) {
    return x * (1.f / (1.f + expf(-x)));
}
__device__ __forceinline__ float softplusf(float x) {
    return (x > 20.f) ? x : log1pf(expf(x));
}
__device__ __forceinline__ void gload_lds16(const void* g, void* l) {
    __builtin_amdgcn_global_load_lds(
        (const __attribute__((address_space(1))) void*)g,
        (__attribute__((address_space(3))) void*)l, 16, 0, 0);
}

// ---------------- Kernel 1: LayerNorm + FiLM -> bf16 ----------------
__global__ void ln_film_kernel(const float* __restrict__ x,
                               const float* __restrict__ gamma,
                               const float* __restrict__ beta,
                               const float* __restrict__ ln_g,
                               const float* __restrict__ ln_b,
                               __hip_bfloat16* __restrict__ xn)
{
    int r = blockIdx.x;            // 0..M-1 (b*L + l)
    int b = r / LL;
    const float* xr = x + (size_t)r * DD;
    int tid = threadIdx.x;

    float v[3];
    float s = 0.f, ss = 0.f;
#pragma unroll
    for (int j = 0; j < 3; ++j) {
        v[j] = xr[tid + j * 256];
        s += v[j];
        ss += v[j] * v[j];
    }
#pragma unroll
    for (int o = 32; o >= 1; o >>= 1) {
        s  += __shfl_xor(s, o, 64);
        ss += __shfl_xor(ss, o, 64);
    }
    __shared__ float ws_s[4], ws_ss[4];
    int wave = tid >> 6;
    if ((tid & 63) == 0) { ws_s[wave] = s; ws_ss[wave] = ss; }
    __syncthreads();
    float tot_s  = ws_s[0] + ws_s[1] + ws_s[2] + ws_s[3];
    float tot_ss = ws_ss[0] + ws_ss[1] + ws_ss[2] + ws_ss[3];
    float mu  = tot_s * (1.f / DD);
    float var = tot_ss * (1.f / DD) - mu * mu;
    float inv = rsqrtf(var + 1e-5f);

#pragma unroll
    for (int j = 0; j < 3; ++j) {
        int i = tid + j * 256;
        float xv = (v[j] - mu) * inv * ln_g[i] + ln_b[i];
        xv = xv * gamma[b * DD + i] + beta[b * DD + i];
        xn[(size_t)r * DD + i] = __float2bfloat16(xv);
    }
}

// ---------------- cast f32 -> bf16 (n % 4 == 0) ----------------
__global__ void cast_bf16_kernel(const float* __restrict__ s,
                                 __hip_bfloat16* __restrict__ d, int n)
{
    int i = (blockIdx.x * 256 + threadIdx.x) * 4;
    if (i >= n) return;
    float4 v = *reinterpret_cast<const float4*>(&s[i]);
    d[i + 0] = __float2bfloat16(v.x);
    d[i + 1] = __float2bfloat16(v.y);
    d[i + 2] = __float2bfloat16(v.z);
    d[i + 3] = __float2bfloat16(v.w);
}

// ---------------- bf16 MFMA GEMM: C[M,N] = A[M,K] * W[N,K]^T ----------------
// 128x128 tile, BK=32, 4 waves each owning 64x64 (4x4 frags of 16x16x32).
// Requires: M%128==0, N%128==0, K%32==0, A/W 16B-aligned.
// EPI 0: store f32; EPI 2: +resid then store f32.
template<int EPI>
__global__ __launch_bounds__(256)
void gemm_mfma_kernel(const __hip_bfloat16* __restrict__ A, int lda,
                      const __hip_bfloat16* __restrict__ W, int ldw,
                      float* __restrict__ C, int ldc, int K,
                      const float* __restrict__ resid)
{
    __shared__ __align__(16) short As[128 * 32];
    __shared__ __align__(16) short Bs[128 * 32];
    const int m0 = blockIdx.y * 128;
    const int n0 = blockIdx.x * 128;
    const int t = threadIdx.x;
    const int lane = t & 63;
    const int w = t >> 6;
    const int wr = w >> 1, wc = w & 1;
    const int lr = lane & 15;
    const int k8 = (lane >> 4) * 8;
    // staging: thread covers row t/4 (and t/4+64), k-col (t&3)*8, 16B each
    const int srow = t >> 2;
    const int scol = (t & 3) * 8;

    f32x4 acc[4][4] = {};

    for (int k0 = 0; k0 < K; k0 += 32) {
        gload_lds16(&A[(size_t)(m0 + srow) * lda + k0 + scol],      &As[t * 8]);
        gload_lds16(&A[(size_t)(m0 + 64 + srow) * lda + k0 + scol], &As[2048 + t * 8]);
        gload_lds16(&W[(size_t)(n0 + srow) * ldw + k0 + scol],      &Bs[t * 8]);
        gload_lds16(&W[(size_t)(n0 + 64 + srow) * ldw + k0 + scol], &Bs[2048 + t * 8]);
        __syncthreads();   // drains vmcnt(0) before barrier

        frag8 a[4], b[4];
#pragma unroll
        for (int i = 0; i < 4; ++i)
            a[i] = *reinterpret_cast<const frag8*>(&As[(wr * 64 + i * 16 + lr) * 32 + k8]);
#pragma unroll
        for (int j = 0; j < 4; ++j)
            b[j] = *reinterpret_cast<const frag8*>(&Bs[(wc * 64 + j * 16 + lr) * 32 + k8]);
#pragma unroll
        for (int i = 0; i < 4; ++i)
#pragma unroll
            for (int j = 0; j < 4; ++j)
                acc[i][j] = __builtin_amdgcn_mfma_f32_16x16x32_bf16(a[i], b[j], acc[i][j], 0, 0, 0);
        __syncthreads();
    }

    const int rowg = (lane >> 4) * 4;
#pragma unroll
    for (int i = 0; i < 4; ++i) {
#pragma unroll
        for (int j = 0; j < 4; ++j) {
#pragma unroll
            for (int r = 0; r < 4; ++r) {
                int m = m0 + wr * 64 + i * 16 + rowg + r;
                int n = n0 + wc * 64 + j * 16 + lr;
                float v = acc[i][j][r];
                if (EPI == 2) v += resid[(size_t)m * ldc + n];
                C[(size_t)m * ldc + n] = v;
            }
        }
    }
}

// ---------------- Generic f32 GEMM (kept for small GEMMs) ----------------
// EPI 0: plain store; EPI 1: +bias then softplus
template<int EPI>
__global__ void gemm_tn_kernel(const float* __restrict__ A, int lda,
                               const float* __restrict__ W,
                               float* __restrict__ C, int ldc,
                               int M, int N, int K,
                               const float* __restrict__ bias)
{
    __shared__ __align__(16) float Asm[16][68];
    __shared__ __align__(16) float Wsm[16][68];
    int m0 = blockIdx.y * 64;
    int n0 = blockIdx.x * 64;
    int tid = threadIdx.x;
    int tx = tid & 15;
    int ty = tid >> 4;
    int lk = tid & 15;
    int lm = tid >> 4;

    float acc[4][4] = {};

    for (int k0 = 0; k0 < K; k0 += 16) {
#pragma unroll
        for (int j = 0; j < 4; ++j) {
            int m = m0 + lm + j * 16;
            Asm[lk][lm + j * 16] = (m < M) ? A[(size_t)m * lda + (k0 + lk)] : 0.f;
        }
#pragma unroll
        for (int j = 0; j < 4; ++j) {
            int n = n0 + lm + j * 16;
            Wsm[lk][lm + j * 16] = (n < N) ? W[(size_t)n * K + (k0 + lk)] : 0.f;
        }
        __syncthreads();
#pragma unroll
        for (int kk = 0; kk < 16; ++kk) {
            float a[4], wv[4];
#pragma unroll
            for (int i = 0; i < 4; ++i) a[i] = Asm[kk][ty * 4 + i];
#pragma unroll
            for (int i = 0; i < 4; ++i) wv[i] = Wsm[kk][tx * 4 + i];
#pragma unroll
            for (int i = 0; i < 4; ++i)
#pragma unroll
                for (int j = 0; j < 4; ++j)
                    acc[i][j] = fmaf(a[i], wv[j], acc[i][j]);
        }
        __syncthreads();
    }

#pragma unroll
    for (int i = 0; i < 4; ++i) {
        int m = m0 + ty * 4 + i;
        if (m >= M) continue;
#pragma unroll
        for (int j = 0; j < 4; ++j) {
            int n = n0 + tx * 4 + j;
            if (n >= N) continue;
            float v = acc[i][j];
            if (EPI == 1) v = softplusf(v + bias[n]);
            C[(size_t)m * ldc + n] = v;
        }
    }
}

// ---------------- Kernel 3: causal depthwise conv + SiLU ----------------
__global__ void conv_silu_kernel(const float* __restrict__ xz,  // [M, 2*DN]
                                 const float* __restrict__ cw,  // [DN,4]
                                 const float* __restrict__ cb,  // [DN]
                                 float* __restrict__ xin)       // [M, DN]
{
    int idx = blockIdx.x * blockDim.x + threadIdx.x;
    if (idx >= MM * DN) return;
    int dn = idx % DN;
    int r  = idx / DN;
    int l  = r % LL;
    float acc = cb[dn];
#pragma unroll
    for (int k = 0; k < 4; ++k) {
        int lt = l - 3 + k;
        if (lt >= 0)
            acc = fmaf(xz[(size_t)(r - 3 + k) * (2 * DN) + dn], cw[dn * 4 + k], acc);
    }
    xin[idx] = siluf(acc);
}

// ---------------- Kernel 5: chunked parallel selective scan ----------------
__global__ void scan_kernel(const float* __restrict__ dt,    // [B,L,DN]
                            const float* __restrict__ xdbl,  // [B,L,80]
                            const float* __restrict__ xin,   // [B,L,DN]
                            const float* __restrict__ A_log, // [DN,16]
                            float* __restrict__ ys)          // [B,L,DN]
{
    int c = blockIdx.x;              // 0..B*DN-1
    int b = c / DN;
    int dn = c % DN;
    int tid = threadIdx.x;
    int lane_n = tid & 15;
    int chunk  = tid >> 4;

    float A = -expf(A_log[dn * NS + lane_n]);

    const size_t base = (size_t)b * LL * DN + dn;
    const float* dt_p = dt  + base;
    const float* u_p  = xin + base;
    const float* B_p  = xdbl + (size_t)b * LL * 80 + DTR + lane_n;
    const float* C_p  = B_p + NS;
    float* y_p = ys + base;

    int t0 = chunk * CHUNK;

    float h = 0.f, aprod = 1.f;
    for (int t = t0; t < t0 + CHUNK; ++t) {
        float dtv = dt_p[(size_t)t * DN];
        float u   = u_p[(size_t)t * DN];
        float Bv  = B_p[(size_t)t * 80];
        float dA  = expf(dtv * A);
        h = fmaf(h, dA, dtv * Bv * u);
        aprod *= dA;
    }
    __shared__ float sh_h[NCHUNK][NS];
    __shared__ float sh_a[NCHUNK][NS];
    sh_h[chunk][lane_n] = h;
    sh_a[chunk][lane_n] = aprod;
    __syncthreads();

    float H0 = 0.f;
    for (int cc = 0; cc < chunk; ++cc)
        H0 = fmaf(sh_a[cc][lane_n], H0, sh_h[cc][lane_n]);

    h = H0;
    for (int t = t0; t < t0 + CHUNK; ++t) {
        float dtv = dt_p[(size_t)t * DN];
        float u   = u_p[(size_t)t * DN];
        float Bv  = B_p[(size_t)t * 80];
        float Cv  = C_p[(size_t)t * 80];
        float dA  = expf(dtv * A);
        h = fmaf(h, dA, dtv * Bv * u);
        float p = h * Cv;
        p += __shfl_xor(p, 1, 64);
        p += __shfl_xor(p, 2, 64);
        p += __shfl_xor(p, 4, 64);
        p += __shfl_xor(p, 8, 64);
        if (lane_n == 0) y_p[(size_t)t * DN] = p;
    }
}

// ---------------- Kernel 6a: gate -> bf16 ----------------
__global__ void gate_kernel(const float* __restrict__ ys,
                            const float* __restrict__ xin,
                            const float* __restrict__ xz,   // z at [:, DN:2DN]
                            const float* __restrict__ Dp,
                            __hip_bfloat16* __restrict__ yg)
{
    int idx = blockIdx.x * blockDim.x + threadIdx.x;
    if (idx >= MM * DN) return;
    int dn = idx % DN;
    int r  = idx / DN;
    float z = xz[(size_t)r * (2 * DN) + DN + dn];
    float y = ys[idx] + Dp[dn] * xin[idx];
    yg[idx] = __float2bfloat16(y * siluf(z));
}

extern "C" void kernel_launch(void* const* d_in, const int* in_sizes, int n_in,
                              void* d_out, int out_size, void* d_ws, size_t ws_size,
                              hipStream_t stream) {
    const float* x         = (const float*)d_in[0];
    const float* gamma     = (const float*)d_in[1];
    const float* beta      = (const float*)d_in[2];
    const float* ln_g      = (const float*)d_in[3];
    const float* ln_b      = (const float*)d_in[4];
    const float* in_proj_w = (const float*)d_in[5];
    const float* conv_w    = (const float*)d_in[6];
    const float* conv_b    = (const float*)d_in[7];
    const float* x_proj_w  = (const float*)d_in[8];
    const float* dt_proj_w = (const float*)d_in[9];
    const float* dt_proj_b = (const float*)d_in[10];
    const float* A_log     = (const float*)d_in[11];
    const float* Dp        = (const float*)d_in[12];
    const float* out_proj_w= (const float*)d_in[13];
    float* out = (float*)d_out;

    char* ws = (char*)d_ws;
    float* xz   = (float*)(ws);                         // 50,331,648 B
    float* xin  = (float*)(ws + 50331648);              // 25,165,824 B
    float* xdbl = (float*)(ws + 75497472);              //  1,310,720 B
    float* dt   = (float*)(ws + 76808192);              // 25,165,824 B
    float* ys   = (float*)(ws + 101974016);             // 25,165,824 B
    __hip_bfloat16* xn_bf = (__hip_bfloat16*)(ws + 127139840);  // 6,291,456 B
    __hip_bfloat16* w1_bf = (__hip_bfloat16*)(ws + 133431296);  // 4,718,592 B -> ends 138,149,888
    // aliases into dead buffers:
    __hip_bfloat16* yg_bf = (__hip_bfloat16*)dt;        // 12.6MB into dt (dead after scan)
    __hip_bfloat16* w2_bf = (__hip_bfloat16*)ys;        // 2.4MB into ys (dead after gate)

    // 1. LN + FiLM -> bf16
    ln_film_kernel<<<MM, 256, 0, stream>>>(x, gamma, beta, ln_g, ln_b, xn_bf);

    // 1b. cast in_proj_w -> bf16
    cast_bf16_kernel<<<(2 * DN * DD / 4 + 255) / 256, 256, 0, stream>>>(in_proj_w, w1_bf, 2 * DN * DD);

    // 2. xz = xn @ in_proj_w^T   [4096 x 3072], K=768  (bf16 MFMA)
    gemm_mfma_kernel<0><<<dim3(3072 / 128, MM / 128), 256, 0, stream>>>(
        xn_bf, DD, w1_bf, DD, xz, 2 * DN, DD, nullptr);

    // 3. conv + silu -> xin
    conv_silu_kernel<<<(MM * DN + 255) / 256, 256, 0, stream>>>(xz, conv_w, conv_b, xin);

    // 4a. x_dbl = xin @ x_proj_w^T   [4096 x 80]  (f32)
    gemm_tn_kernel<0><<<dim3(2, MM / 64), 256, 0, stream>>>(
        xin, DN, x_proj_w, xdbl, 80, MM, 80, DN, nullptr);

    // 4b. dt = softplus(x_dbl[:, :48] @ dt_proj_w^T + b)   [4096 x 1536]  (f32)
    gemm_tn_kernel<1><<<dim3(DN / 64, MM / 64), 256, 0, stream>>>(
        xdbl, 80, dt_proj_w, dt, DN, MM, DN, DTR, dt_proj_b);

    // 5. chunked parallel selective scan -> ys
    scan_kernel<<<BB * DN, 256, 0, stream>>>(dt, xdbl, xin, A_log, ys);

    // 6a. gate -> bf16 (into dt slot; dt is dead)
    gate_kernel<<<(MM * DN + 255) / 256, 256, 0, stream>>>(ys, xin, xz, Dp, yg_bf);

    // 6b-pre. cast out_proj_w -> bf16 (into ys slot; ys is dead)
    cast_bf16_kernel<<<(DD * DN / 4 + 255) / 256, 256, 0, stream>>>(out_proj_w, w2_bf, DD * DN);

    // 6b. out = x + yg @ out_proj_w^T   [4096 x 768], K=1536  (bf16 MFMA)
    gemm_mfma_kernel<2><<<dim3(DD / 128, MM / 128), 256, 0, stream>>>(
        yg_bf, DN, w2_bf, DN, out, DD, DN, x);
}

// Round 5
// 669.613 us; speedup vs baseline: 2.7854x; 1.0573x over previous
//
#include <hip/hip_runtime.h>
#include <hip/hip_bf16.h>
#include <math.h>

#define BB 2
#define LL 2048
#define DD 768
#define DN 1536
#define NS 16
#define DTR 48
#define MM (BB*LL)   // 4096
#define CHUNK 128
#define NCHUNK 16    // LL / CHUNK

using frag8 = __attribute__((ext_vector_type(8))) short;   // 8 bf16 (4 VGPRs)
using f32x4 = __attribute__((ext_vector_type(4))) float;

__device__ __forceinline__ float siluf(float x) {
    return x * (1.f / (1.f + expf(-x)));
}
__device__ __forceinline__ float softplusf(float x) {
    return (x > 20.f) ? x : log1pf(expf(x));
}
__device__ __forceinline__ void gload_lds16(const void* g, void* l) {
    __builtin_amdgcn_global_load_lds(
        (const __attribute__((address_space(1))) void*)g,
        (__attribute__((address_space(3))) void*)l, 16, 0, 0);
}

// ---------------- Kernel 1: LayerNorm + FiLM -> bf16 ----------------
__global__ void ln_film_kernel(const float* __restrict__ x,
                               const float* __restrict__ gamma,
                               const float* __restrict__ beta,
                               const float* __restrict__ ln_g,
                               const float* __restrict__ ln_b,
                               __hip_bfloat16* __restrict__ xn)
{
    int r = blockIdx.x;            // 0..M-1 (b*L + l)
    int b = r / LL;
    const float* xr = x + (size_t)r * DD;
    int tid = threadIdx.x;

    float v[3];
    float s = 0.f, ss = 0.f;
#pragma unroll
    for (int j = 0; j < 3; ++j) {
        v[j] = xr[tid + j * 256];
        s += v[j];
        ss += v[j] * v[j];
    }
#pragma unroll
    for (int o = 32; o >= 1; o >>= 1) {
        s  += __shfl_xor(s, o, 64);
        ss += __shfl_xor(ss, o, 64);
    }
    __shared__ float ws_s[4], ws_ss[4];
    int wave = tid >> 6;
    if ((tid & 63) == 0) { ws_s[wave] = s; ws_ss[wave] = ss; }
    __syncthreads();
    float tot_s  = ws_s[0] + ws_s[1] + ws_s[2] + ws_s[3];
    float tot_ss = ws_ss[0] + ws_ss[1] + ws_ss[2] + ws_ss[3];
    float mu  = tot_s * (1.f / DD);
    float var = tot_ss * (1.f / DD) - mu * mu;
    float inv = rsqrtf(var + 1e-5f);

#pragma unroll
    for (int j = 0; j < 3; ++j) {
        int i = tid + j * 256;
        float xv = (v[j] - mu) * inv * ln_g[i] + ln_b[i];
        xv = xv * gamma[b * DD + i] + beta[b * DD + i];
        xn[(size_t)r * DD + i] = __float2bfloat16(xv);
    }
}

// ---------------- cast f32 -> bf16 (n % 4 == 0) ----------------
__global__ void cast_bf16_kernel(const float* __restrict__ s,
                                 __hip_bfloat16* __restrict__ d, int n)
{
    int i = (blockIdx.x * 256 + threadIdx.x) * 4;
    if (i >= n) return;
    float4 v = *reinterpret_cast<const float4*>(&s[i]);
    d[i + 0] = __float2bfloat16(v.x);
    d[i + 1] = __float2bfloat16(v.y);
    d[i + 2] = __float2bfloat16(v.z);
    d[i + 3] = __float2bfloat16(v.w);
}

// ---------------- bf16 MFMA GEMM: C[M,N] = A[M,K] * W[N,K]^T ----------------
// 128x128 tile, BK=32, 4 waves each owning 64x64 (4x4 frags of 16x16x32).
// EPI 0: store f32; EPI 2: +resid then store f32.
template<int EPI>
__global__ __launch_bounds__(256)
void gemm_mfma_kernel(const __hip_bfloat16* __restrict__ A, int lda,
                      const __hip_bfloat16* __restrict__ W, int ldw,
                      float* __restrict__ C, int ldc, int K,
                      const float* __restrict__ resid)
{
    __shared__ __align__(16) short As[128 * 32];
    __shared__ __align__(16) short Bs[128 * 32];
    const int m0 = blockIdx.y * 128;
    const int n0 = blockIdx.x * 128;
    const int t = threadIdx.x;
    const int lane = t & 63;
    const int w = t >> 6;
    const int wr = w >> 1, wc = w & 1;
    const int lr = lane & 15;
    const int k8 = (lane >> 4) * 8;
    const int srow = t >> 2;
    const int scol = (t & 3) * 8;

    f32x4 acc[4][4] = {};

    for (int k0 = 0; k0 < K; k0 += 32) {
        gload_lds16(&A[(size_t)(m0 + srow) * lda + k0 + scol],      &As[t * 8]);
        gload_lds16(&A[(size_t)(m0 + 64 + srow) * lda + k0 + scol], &As[2048 + t * 8]);
        gload_lds16(&W[(size_t)(n0 + srow) * ldw + k0 + scol],      &Bs[t * 8]);
        gload_lds16(&W[(size_t)(n0 + 64 + srow) * ldw + k0 + scol], &Bs[2048 + t * 8]);
        __syncthreads();

        frag8 a[4], b[4];
#pragma unroll
        for (int i = 0; i < 4; ++i)
            a[i] = *reinterpret_cast<const frag8*>(&As[(wr * 64 + i * 16 + lr) * 32 + k8]);
#pragma unroll
        for (int j = 0; j < 4; ++j)
            b[j] = *reinterpret_cast<const frag8*>(&Bs[(wc * 64 + j * 16 + lr) * 32 + k8]);
#pragma unroll
        for (int i = 0; i < 4; ++i)
#pragma unroll
            for (int j = 0; j < 4; ++j)
                acc[i][j] = __builtin_amdgcn_mfma_f32_16x16x32_bf16(a[i], b[j], acc[i][j], 0, 0, 0);
        __syncthreads();
    }

    const int rowg = (lane >> 4) * 4;
#pragma unroll
    for (int i = 0; i < 4; ++i) {
#pragma unroll
        for (int j = 0; j < 4; ++j) {
#pragma unroll
            for (int r = 0; r < 4; ++r) {
                int m = m0 + wr * 64 + i * 16 + rowg + r;
                int n = n0 + wc * 64 + j * 16 + lr;
                float v = acc[i][j][r];
                if (EPI == 2) v += resid[(size_t)m * ldc + n];
                C[(size_t)m * ldc + n] = v;
            }
        }
    }
}

// ---------------- Generic f32 GEMM ----------------
// EPI 0: plain store C[m,n].
// EPI 3: softplus(v + bias[n]) stored TRANSPOSED time-major: C[(b*DN+n)*LL + l].
template<int EPI>
__global__ void gemm_tn_kernel(const float* __restrict__ A, int lda,
                               const float* __restrict__ W,
                               float* __restrict__ C, int ldc,
                               int M, int N, int K,
                               const float* __restrict__ bias)
{
    __shared__ __align__(16) float Asm[16][68];
    __shared__ __align__(16) float Wsm[16][68];
    int m0 = blockIdx.y * 64;
    int n0 = blockIdx.x * 64;
    int tid = threadIdx.x;
    int tx = tid & 15;
    int ty = tid >> 4;
    int lk = tid & 15;
    int lm = tid >> 4;

    float acc[4][4] = {};

    for (int k0 = 0; k0 < K; k0 += 16) {
#pragma unroll
        for (int j = 0; j < 4; ++j) {
            int m = m0 + lm + j * 16;
            Asm[lk][lm + j * 16] = (m < M) ? A[(size_t)m * lda + (k0 + lk)] : 0.f;
        }
#pragma unroll
        for (int j = 0; j < 4; ++j) {
            int n = n0 + lm + j * 16;
            Wsm[lk][lm + j * 16] = (n < N) ? W[(size_t)n * K + (k0 + lk)] : 0.f;
        }
        __syncthreads();
#pragma unroll
        for (int kk = 0; kk < 16; ++kk) {
            float a[4], wv[4];
#pragma unroll
            for (int i = 0; i < 4; ++i) a[i] = Asm[kk][ty * 4 + i];
#pragma unroll
            for (int i = 0; i < 4; ++i) wv[i] = Wsm[kk][tx * 4 + i];
#pragma unroll
            for (int i = 0; i < 4; ++i)
#pragma unroll
                for (int j = 0; j < 4; ++j)
                    acc[i][j] = fmaf(a[i], wv[j], acc[i][j]);
        }
        __syncthreads();
    }

#pragma unroll
    for (int i = 0; i < 4; ++i) {
        int m = m0 + ty * 4 + i;
        if (m >= M) continue;
#pragma unroll
        for (int j = 0; j < 4; ++j) {
            int n = n0 + tx * 4 + j;
            if (n >= N) continue;
            float v = acc[i][j];
            if (EPI == 3) {
                v = softplusf(v + bias[n]);
                int b = m / LL, l = m % LL;
                C[((size_t)b * DN + n) * LL + l] = v;
            } else {
                C[(size_t)m * ldc + n] = v;
            }
        }
    }
}

// ---------------- transpose z-half of xz: [M, 2DN] -> z_T [B,DN,L] ----------------
__global__ void transpose_z_kernel(const float* __restrict__ xz,
                                   float* __restrict__ zT)
{
    __shared__ float t[64][65];
    int l0 = blockIdx.x * 64, dn0 = blockIdx.y * 64, b = blockIdx.z;
    int col = threadIdx.x & 63;
    for (int r = threadIdx.x >> 6; r < 64; r += 4)
        t[r][col] = xz[((size_t)(b * LL + l0 + r)) * 2 * DN + DN + dn0 + col];
    __syncthreads();
    for (int r = threadIdx.x >> 6; r < 64; r += 4)
        zT[((size_t)(b * DN + dn0 + r)) * LL + l0 + col] = t[col][r];
}

// ---------------- tiled causal depthwise conv + SiLU, dual-layout output ----------
// Block: 64 l x 64 dn tile. Emits xin [M,DN] and xin_T [B,DN,L].
__global__ void conv_silu_tile_kernel(const float* __restrict__ xz,  // [M,2DN], x-part
                                      const float* __restrict__ cw,  // [DN,4]
                                      const float* __restrict__ cb,  // [DN]
                                      float* __restrict__ xin,       // [M,DN]
                                      float* __restrict__ xinT)      // [B,DN,L]
{
    __shared__ float in[67][65];
    __shared__ float res[64][65];
    int l0 = blockIdx.x * 64, dn0 = blockIdx.y * 64, b = blockIdx.z;
    int tid = threadIdx.x;
    int col = tid & 63;
    for (int r = tid >> 6; r < 67; r += 4) {
        int l = l0 - 3 + r;
        in[r][col] = (l >= 0) ? xz[((size_t)(b * LL + l)) * 2 * DN + dn0 + col] : 0.f;
    }
    __syncthreads();
    // compute: lanes dn-major (col = dn), each thread 16 consecutive l
    {
        int dnl = col;
        float w0 = cw[(dn0 + dnl) * 4 + 0], w1 = cw[(dn0 + dnl) * 4 + 1];
        float w2 = cw[(dn0 + dnl) * 4 + 2], w3 = cw[(dn0 + dnl) * 4 + 3];
        float bv = cb[dn0 + dnl];
        int lbase = (tid >> 6) * 16;
#pragma unroll
        for (int i = 0; i < 16; ++i) {
            int lr = lbase + i;
            float acc = bv;
            acc = fmaf(in[lr + 0][dnl], w0, acc);
            acc = fmaf(in[lr + 1][dnl], w1, acc);
            acc = fmaf(in[lr + 2][dnl], w2, acc);
            acc = fmaf(in[lr + 3][dnl], w3, acc);
            res[lr][dnl] = siluf(acc);
        }
    }
    __syncthreads();
    // write normal layout: lanes dn-major
    {
        int dnl = col, lbase = (tid >> 6) * 16;
#pragma unroll
        for (int i = 0; i < 16; ++i) {
            int lr = lbase + i;
            xin[((size_t)(b * LL + l0 + lr)) * DN + dn0 + dnl] = res[lr][dnl];
        }
    }
    // write transposed layout: lanes l-major
    {
        int ll = col, dbase = (tid >> 6) * 16;
#pragma unroll
        for (int i = 0; i < 16; ++i) {
            int dnl = dbase + i;
            xinT[((size_t)(b * DN + dn0 + dnl)) * LL + l0 + ll] = res[ll][dnl];
        }
    }
}

// ---------------- chunked parallel selective scan + fused gate ----------------
// Time-major inputs. One block per (b,dn); 16 chunks x 16 state-lanes.
// Phase 3 fuses: y = (sum_h + Dp*u) * silu(z), written bf16 time-major.
__global__ void scan_kernel(const float* __restrict__ dtT,   // [B,DN,L]
                            const float* __restrict__ xdbl,  // [B,L,80]
                            const float* __restrict__ uT,    // [B,DN,L]
                            const float* __restrict__ zT,    // [B,DN,L]
                            const float* __restrict__ A_log, // [DN,16]
                            const float* __restrict__ Dp,    // [DN]
                            __hip_bfloat16* __restrict__ ygT)// [B,DN,L]
{
    int c = blockIdx.x;              // 0..B*DN-1
    int b = c / DN;
    int dn = c % DN;
    int tid = threadIdx.x;
    int lane_n = tid & 15;
    int chunk  = tid >> 4;

    float A = -expf(A_log[dn * NS + lane_n]);
    float Dpv = Dp[dn];

    const size_t baseT = ((size_t)b * DN + dn) * LL;
    const float* dt_p = dtT + baseT;
    const float* u_p  = uT  + baseT;
    const float* z_p  = zT  + baseT;
    const float* B_p  = xdbl + (size_t)b * LL * 80 + DTR + lane_n;
    const float* C_p  = B_p + NS;
    __hip_bfloat16* y_p = ygT + baseT;

    int t0 = chunk * CHUNK;

    // Phase 1: local scan from zero state
    float h = 0.f, aprod = 1.f;
    for (int t = t0; t < t0 + CHUNK; ++t) {
        float dtv = dt_p[t];
        float u   = u_p[t];
        float Bv  = B_p[(size_t)t * 80];
        float dA  = expf(dtv * A);
        h = fmaf(h, dA, dtv * Bv * u);
        aprod *= dA;
    }
    __shared__ float sh_h[NCHUNK][NS];
    __shared__ float sh_a[NCHUNK][NS];
    sh_h[chunk][lane_n] = h;
    sh_a[chunk][lane_n] = aprod;
    __syncthreads();

    // Phase 2: combine preceding chunk summaries
    float H0 = 0.f;
    for (int cc = 0; cc < chunk; ++cc)
        H0 = fmaf(sh_a[cc][lane_n], H0, sh_h[cc][lane_n]);

    // Phase 3: re-scan from H0, gate, emit bf16 (coalesced 16-wide)
    h = H0;
    float yv = 0.f;
    for (int t = t0; t < t0 + CHUNK; ++t) {
        float dtv = dt_p[t];
        float u   = u_p[t];
        float Bv  = B_p[(size_t)t * 80];
        float Cv  = C_p[(size_t)t * 80];
        float dA  = expf(dtv * A);
        h = fmaf(h, dA, dtv * Bv * u);
        float p = h * Cv;
        p += __shfl_xor(p, 1, 64);
        p += __shfl_xor(p, 2, 64);
        p += __shfl_xor(p, 4, 64);
        p += __shfl_xor(p, 8, 64);
        float z = z_p[t];
        float val = (p + Dpv * u) * siluf(z);
        if ((t & 15) == lane_n) yv = val;
        if ((t & 15) == 15) y_p[(t & ~15) + lane_n] = __float2bfloat16(yv);
    }
}

// ---------------- bf16 transpose: ygT [B,DN,L] -> yg [M,DN] ----------------
__global__ void transpose_yg_kernel(const __hip_bfloat16* __restrict__ ygT,
                                    __hip_bfloat16* __restrict__ yg)
{
    __shared__ unsigned short t[64][65];
    int dn0 = blockIdx.x * 64, l0 = blockIdx.y * 64, b = blockIdx.z;
    int col = threadIdx.x & 63;
    const unsigned short* src = (const unsigned short*)ygT;
    unsigned short* dst = (unsigned short*)yg;
    for (int r = threadIdx.x >> 6; r < 64; r += 4)
        t[r][col] = src[((size_t)(b * DN + dn0 + r)) * LL + l0 + col];
    __syncthreads();
    for (int r = threadIdx.x >> 6; r < 64; r += 4)
        dst[((size_t)(b * LL + l0 + r)) * DN + dn0 + col] = t[col][r];
}

extern "C" void kernel_launch(void* const* d_in, const int* in_sizes, int n_in,
                              void* d_out, int out_size, void* d_ws, size_t ws_size,
                              hipStream_t stream) {
    const float* x         = (const float*)d_in[0];
    const float* gamma     = (const float*)d_in[1];
    const float* beta      = (const float*)d_in[2];
    const float* ln_g      = (const float*)d_in[3];
    const float* ln_b      = (const float*)d_in[4];
    const float* in_proj_w = (const float*)d_in[5];
    const float* conv_w    = (const float*)d_in[6];
    const float* conv_b    = (const float*)d_in[7];
    const float* x_proj_w  = (const float*)d_in[8];
    const float* dt_proj_w = (const float*)d_in[9];
    const float* dt_proj_b = (const float*)d_in[10];
    const float* A_log     = (const float*)d_in[11];
    const float* Dp        = (const float*)d_in[12];
    const float* out_proj_w= (const float*)d_in[13];
    float* out = (float*)d_out;

    char* ws = (char*)d_ws;
    float* xz    = (float*)(ws);                        // 50,331,648 B [0, 50.3M)
    float* xin   = (float*)(ws + 50331648);             // 25,165,824 B
    float* xinT  = (float*)(ws + 75497472);             // 25,165,824 B
    float* xdbl  = (float*)(ws + 100663296);            //  1,310,720 B
    float* zT    = (float*)(ws + 101974016);            // 25,165,824 B
    __hip_bfloat16* xn_bf = (__hip_bfloat16*)(ws + 127139840);  // 6,291,456 B
    __hip_bfloat16* w1_bf = (__hip_bfloat16*)(ws + 133431296);  // 4,718,592 B -> 138,149,888
    // aliases into xz (dead after conv):
    float* dtT = (float*)(ws);                          // 25,165,824 B
    __hip_bfloat16* ygT = (__hip_bfloat16*)(ws + 25165824);   // 12,582,912 B
    __hip_bfloat16* yg  = (__hip_bfloat16*)(ws + 37748736);   // 12,582,912 B
    // alias into xn_bf (dead after in_proj GEMM):
    __hip_bfloat16* w2_bf = xn_bf;                      // 2,359,296 B <= 6,291,456 B

    // 1. LN + FiLM -> bf16
    ln_film_kernel<<<MM, 256, 0, stream>>>(x, gamma, beta, ln_g, ln_b, xn_bf);

    // 1b. cast in_proj_w -> bf16
    cast_bf16_kernel<<<(2 * DN * DD / 4 + 255) / 256, 256, 0, stream>>>(in_proj_w, w1_bf, 2 * DN * DD);

    // 2. xz = xn @ in_proj_w^T   [4096 x 3072], K=768  (bf16 MFMA)
    gemm_mfma_kernel<0><<<dim3(3072 / 128, MM / 128), 256, 0, stream>>>(
        xn_bf, DD, w1_bf, DD, xz, 2 * DN, DD, nullptr);

    // 2b. transpose z-half -> zT [B,DN,L]
    transpose_z_kernel<<<dim3(LL / 64, DN / 64, BB), 256, 0, stream>>>(xz, zT);

    // 3. tiled conv + silu -> xin (normal) + xinT (time-major); xz dead after
    conv_silu_tile_kernel<<<dim3(LL / 64, DN / 64, BB), 256, 0, stream>>>(
        xz, conv_w, conv_b, xin, xinT);

    // 4a. x_dbl = xin @ x_proj_w^T   [4096 x 80]  (f32)
    gemm_tn_kernel<0><<<dim3(2, MM / 64), 256, 0, stream>>>(
        xin, DN, x_proj_w, xdbl, 80, MM, 80, DN, nullptr);

    // 4b. dtT = softplus(x_dbl[:, :48] @ dt_proj_w^T + b), stored [B,DN,L]
    gemm_tn_kernel<3><<<dim3(DN / 64, MM / 64), 256, 0, stream>>>(
        xdbl, 80, dt_proj_w, dtT, 0, MM, DN, DTR, dt_proj_b);

    // 5. scan + fused gate -> ygT (bf16, time-major)
    scan_kernel<<<BB * DN, 256, 0, stream>>>(dtT, xdbl, xinT, zT, A_log, Dp, ygT);

    // 5b. transpose ygT -> yg [M,DN]
    transpose_yg_kernel<<<dim3(DN / 64, LL / 64, BB), 256, 0, stream>>>(ygT, yg);

    // 6-pre. cast out_proj_w -> bf16
    cast_bf16_kernel<<<(DD * DN / 4 + 255) / 256, 256, 0, stream>>>(out_proj_w, w2_bf, DD * DN);

    // 6. out = x + yg @ out_proj_w^T   [4096 x 768], K=1536  (bf16 MFMA)
    gemm_mfma_kernel<2><<<dim3(DD / 128, MM / 128), 256, 0, stream>>>(
        yg, DN, w2_bf, DN, out, DD, DN, x);
}

// Round 7
// 480.207 us; speedup vs baseline: 3.8840x; 1.3944x over previous
//
#include <hip/hip_runtime.h>
#include <hip/hip_bf16.h>
#include <math.h>

#define BB 2
#define LL 2048
#define DD 768
#define DN 1536
#define NS 16
#define DTR 48
#define MM (BB*LL)   // 4096
#define SCHUNK 32    // time-steps per lane in scan
#define KSPLIT 8
#define KCH (DN / KSPLIT)   // 192

using frag8 = __attribute__((ext_vector_type(8))) short;   // 8 bf16 (4 VGPRs)
using f32x4 = __attribute__((ext_vector_type(4))) float;

#define LOG2E 1.4426950408889634f

__device__ __forceinline__ float siluf(float x) {
    // x * sigmoid(x) with fast rcp (v_rcp_f32, ~1ulp) instead of precise div
    return x * __builtin_amdgcn_rcpf(1.f + exp2f(-x * LOG2E));
}
__device__ __forceinline__ float softplusf(float x) {
    return (x > 20.f) ? x : log1pf(expf(x));
}
__device__ __forceinline__ void gload_lds16(const void* g, void* l) {
    __builtin_amdgcn_global_load_lds(
        (const __attribute__((address_space(1))) void*)g,
        (__attribute__((address_space(3))) void*)l, 16, 0, 0);
}

// ---------------- Kernel 1: LayerNorm + FiLM -> bf16 ----------------
__global__ void ln_film_kernel(const float* __restrict__ x,
                               const float* __restrict__ gamma,
                               const float* __restrict__ beta,
                               const float* __restrict__ ln_g,
                               const float* __restrict__ ln_b,
                               __hip_bfloat16* __restrict__ xn)
{
    int r = blockIdx.x;
    int b = r / LL;
    const float* xr = x + (size_t)r * DD;
    int tid = threadIdx.x;

    float v[3];
    float s = 0.f, ss = 0.f;
#pragma unroll
    for (int j = 0; j < 3; ++j) {
        v[j] = xr[tid + j * 256];
        s += v[j];
        ss += v[j] * v[j];
    }
#pragma unroll
    for (int o = 32; o >= 1; o >>= 1) {
        s  += __shfl_xor(s, o, 64);
        ss += __shfl_xor(ss, o, 64);
    }
    __shared__ float ws_s[4], ws_ss[4];
    int wave = tid >> 6;
    if ((tid & 63) == 0) { ws_s[wave] = s; ws_ss[wave] = ss; }
    __syncthreads();
    float tot_s  = ws_s[0] + ws_s[1] + ws_s[2] + ws_s[3];
    float tot_ss = ws_ss[0] + ws_ss[1] + ws_ss[2] + ws_ss[3];
    float mu  = tot_s * (1.f / DD);
    float var = tot_ss * (1.f / DD) - mu * mu;
    float inv = rsqrtf(var + 1e-5f);

#pragma unroll
    for (int j = 0; j < 3; ++j) {
        int i = tid + j * 256;
        float xv = (v[j] - mu) * inv * ln_g[i] + ln_b[i];
        xv = xv * gamma[b * DD + i] + beta[b * DD + i];
        xn[(size_t)r * DD + i] = __float2bfloat16(xv);
    }
}

// ---------------- cast f32 -> bf16 (n % 4 == 0) ----------------
__global__ void cast_bf16_kernel(const float* __restrict__ s,
                                 __hip_bfloat16* __restrict__ d, int n)
{
    int i = (blockIdx.x * 256 + threadIdx.x) * 4;
    if (i >= n) return;
    float4 v = *reinterpret_cast<const float4*>(&s[i]);
    d[i + 0] = __float2bfloat16(v.x);
    d[i + 1] = __float2bfloat16(v.y);
    d[i + 2] = __float2bfloat16(v.z);
    d[i + 3] = __float2bfloat16(v.w);
}

// ---------------- bf16 MFMA GEMM: C[M,N] = A[M,K] * W[N,K]^T ----------------
template<int EPI>
__global__ __launch_bounds__(256)
void gemm_mfma_kernel(const __hip_bfloat16* __restrict__ A, int lda,
                      const __hip_bfloat16* __restrict__ W, int ldw,
                      float* __restrict__ C, int ldc, int K,
                      const float* __restrict__ resid)
{
    __shared__ __align__(16) short As[128 * 32];
    __shared__ __align__(16) short Bs[128 * 32];
    const int m0 = blockIdx.y * 128;
    const int n0 = blockIdx.x * 128;
    const int t = threadIdx.x;
    const int lane = t & 63;
    const int w = t >> 6;
    const int wr = w >> 1, wc = w & 1;
    const int lr = lane & 15;
    const int k8 = (lane >> 4) * 8;
    const int srow = t >> 2;
    const int scol = (t & 3) * 8;

    f32x4 acc[4][4] = {};

    for (int k0 = 0; k0 < K; k0 += 32) {
        gload_lds16(&A[(size_t)(m0 + srow) * lda + k0 + scol],      &As[t * 8]);
        gload_lds16(&A[(size_t)(m0 + 64 + srow) * lda + k0 + scol], &As[2048 + t * 8]);
        gload_lds16(&W[(size_t)(n0 + srow) * ldw + k0 + scol],      &Bs[t * 8]);
        gload_lds16(&W[(size_t)(n0 + 64 + srow) * ldw + k0 + scol], &Bs[2048 + t * 8]);
        __syncthreads();

        frag8 a[4], b[4];
#pragma unroll
        for (int i = 0; i < 4; ++i)
            a[i] = *reinterpret_cast<const frag8*>(&As[(wr * 64 + i * 16 + lr) * 32 + k8]);
#pragma unroll
        for (int j = 0; j < 4; ++j)
            b[j] = *reinterpret_cast<const frag8*>(&Bs[(wc * 64 + j * 16 + lr) * 32 + k8]);
#pragma unroll
        for (int i = 0; i < 4; ++i)
#pragma unroll
            for (int j = 0; j < 4; ++j)
                acc[i][j] = __builtin_amdgcn_mfma_f32_16x16x32_bf16(a[i], b[j], acc[i][j], 0, 0, 0);
        __syncthreads();
    }

    const int rowg = (lane >> 4) * 4;
#pragma unroll
    for (int i = 0; i < 4; ++i) {
#pragma unroll
        for (int j = 0; j < 4; ++j) {
#pragma unroll
            for (int r = 0; r < 4; ++r) {
                int m = m0 + wr * 64 + i * 16 + rowg + r;
                int n = n0 + wc * 64 + j * 16 + lr;
                float v = acc[i][j][r];
                if (EPI == 2) v += resid[(size_t)m * ldc + n];
                C[(size_t)m * ldc + n] = v;
            }
        }
    }
}

// ---------------- Generic f32 GEMM ----------------
// EPI 0: plain store C[m,n].
// EPI 3: softplus(v + bias[n]) stored TRANSPOSED time-major: C[(b*DN+n)*LL + l].
template<int EPI>
__global__ void gemm_tn_kernel(const float* __restrict__ A, int lda,
                               const float* __restrict__ W,
                               float* __restrict__ C, int ldc,
                               int M, int N, int K,
                               const float* __restrict__ bias)
{
    __shared__ __align__(16) float Asm[16][68];
    __shared__ __align__(16) float Wsm[16][68];
    int m0 = blockIdx.y * 64;
    int n0 = blockIdx.x * 64;
    int tid = threadIdx.x;
    int tx = tid & 15;
    int ty = tid >> 4;
    int lk = tid & 15;
    int lm = tid >> 4;

    float acc[4][4] = {};

    for (int k0 = 0; k0 < K; k0 += 16) {
#pragma unroll
        for (int j = 0; j < 4; ++j) {
            int m = m0 + lm + j * 16;
            Asm[lk][lm + j * 16] = (m < M) ? A[(size_t)m * lda + (k0 + lk)] : 0.f;
        }
#pragma unroll
        for (int j = 0; j < 4; ++j) {
            int n = n0 + lm + j * 16;
            Wsm[lk][lm + j * 16] = (n < N) ? W[(size_t)n * K + (k0 + lk)] : 0.f;
        }
        __syncthreads();
#pragma unroll
        for (int kk = 0; kk < 16; ++kk) {
            float a[4], wv[4];
#pragma unroll
            for (int i = 0; i < 4; ++i) a[i] = Asm[kk][ty * 4 + i];
#pragma unroll
            for (int i = 0; i < 4; ++i) wv[i] = Wsm[kk][tx * 4 + i];
#pragma unroll
            for (int i = 0; i < 4; ++i)
#pragma unroll
                for (int j = 0; j < 4; ++j)
                    acc[i][j] = fmaf(a[i], wv[j], acc[i][j]);
        }
        __syncthreads();
    }

#pragma unroll
    for (int i = 0; i < 4; ++i) {
        int m = m0 + ty * 4 + i;
        if (m >= M) continue;
#pragma unroll
        for (int j = 0; j < 4; ++j) {
            int n = n0 + tx * 4 + j;
            if (n >= N) continue;
            float v = acc[i][j];
            if (EPI == 3) {
                v = softplusf(v + bias[n]);
                int b = m / LL, l = m % LL;
                C[((size_t)b * DN + n) * LL + l] = v;
            } else {
                C[(size_t)m * ldc + n] = v;
            }
        }
    }
}

// ---------------- x_proj GEMM, split-K: part[ks][M][80] ----------------
__global__ void gemm_xproj_splitk(const float* __restrict__ A,   // xin [M,DN]
                                  const float* __restrict__ W,   // [80,DN]
                                  float* __restrict__ part)      // [KSPLIT][M][80]
{
    __shared__ __align__(16) float Asm[16][68];
    __shared__ __align__(16) float Wsm[16][68];
    int ks = blockIdx.z;
    int m0 = blockIdx.y * 64;
    int n0 = blockIdx.x * 64;
    int tid = threadIdx.x;
    int tx = tid & 15;
    int ty = tid >> 4;
    int lk = tid & 15;
    int lm = tid >> 4;

    float acc[4][4] = {};

    for (int k0 = ks * KCH; k0 < (ks + 1) * KCH; k0 += 16) {
#pragma unroll
        for (int j = 0; j < 4; ++j) {
            int m = m0 + lm + j * 16;
            Asm[lk][lm + j * 16] = A[(size_t)m * DN + (k0 + lk)];
        }
#pragma unroll
        for (int j = 0; j < 4; ++j) {
            int n = n0 + lm + j * 16;
            Wsm[lk][lm + j * 16] = (n < 80) ? W[(size_t)n * DN + (k0 + lk)] : 0.f;
        }
        __syncthreads();
#pragma unroll
        for (int kk = 0; kk < 16; ++kk) {
            float a[4], wv[4];
#pragma unroll
            for (int i = 0; i < 4; ++i) a[i] = Asm[kk][ty * 4 + i];
#pragma unroll
            for (int i = 0; i < 4; ++i) wv[i] = Wsm[kk][tx * 4 + i];
#pragma unroll
            for (int i = 0; i < 4; ++i)
#pragma unroll
                for (int j = 0; j < 4; ++j)
                    acc[i][j] = fmaf(a[i], wv[j], acc[i][j]);
        }
        __syncthreads();
    }

#pragma unroll
    for (int i = 0; i < 4; ++i) {
        int m = m0 + ty * 4 + i;
#pragma unroll
        for (int j = 0; j < 4; ++j) {
            int n = n0 + tx * 4 + j;
            if (n >= 80) continue;
            part[((size_t)ks * MM + m) * 80 + n] = acc[i][j];
        }
    }
}

// ---------------- reduce split-K partials -> xdbl [M,80] ----------------
__global__ void reduce_xproj_kernel(const float* __restrict__ part,
                                    float* __restrict__ xdbl)
{
    int i = (blockIdx.x * 256 + threadIdx.x) * 4;
    if (i >= MM * 80) return;
    float4 s = *reinterpret_cast<const float4*>(&part[i]);
#pragma unroll
    for (int k = 1; k < KSPLIT; ++k) {
        float4 v = *reinterpret_cast<const float4*>(&part[(size_t)k * MM * 80 + i]);
        s.x += v.x; s.y += v.y; s.z += v.z; s.w += v.w;
    }
    *reinterpret_cast<float4*>(&xdbl[i]) = s;
}

// ---------------- transpose z-half of xz: [M, 2DN] -> z_T [B,DN,L] ----------------
__global__ void transpose_z_kernel(const float* __restrict__ xz,
                                   float* __restrict__ zT)
{
    __shared__ float t[64][65];
    int l0 = blockIdx.x * 64, dn0 = blockIdx.y * 64, b = blockIdx.z;
    int col = threadIdx.x & 63;
    for (int r = threadIdx.x >> 6; r < 64; r += 4)
        t[r][col] = xz[((size_t)(b * LL + l0 + r)) * 2 * DN + DN + dn0 + col];
    __syncthreads();
    for (int r = threadIdx.x >> 6; r < 64; r += 4)
        zT[((size_t)(b * DN + dn0 + r)) * LL + l0 + col] = t[col][r];
}

// ---------------- tiled causal depthwise conv + SiLU, dual-layout output ----------
__global__ void conv_silu_tile_kernel(const float* __restrict__ xz,  // [M,2DN], x-part
                                      const float* __restrict__ cw,  // [DN,4]
                                      const float* __restrict__ cb,  // [DN]
                                      float* __restrict__ xin,       // [M,DN]
                                      float* __restrict__ xinT)      // [B,DN,L]
{
    __shared__ float in[67][65];
    __shared__ float res[64][65];
    int l0 = blockIdx.x * 64, dn0 = blockIdx.y * 64, b = blockIdx.z;
    int tid = threadIdx.x;
    int col = tid & 63;
    for (int r = tid >> 6; r < 67; r += 4) {
        int l = l0 - 3 + r;
        in[r][col] = (l >= 0) ? xz[((size_t)(b * LL + l)) * 2 * DN + dn0 + col] : 0.f;
    }
    __syncthreads();
    {
        int dnl = col;
        float w0 = cw[(dn0 + dnl) * 4 + 0], w1 = cw[(dn0 + dnl) * 4 + 1];
        float w2 = cw[(dn0 + dnl) * 4 + 2], w3 = cw[(dn0 + dnl) * 4 + 3];
        float bv = cb[dn0 + dnl];
        int lbase = (tid >> 6) * 16;
#pragma unroll
        for (int i = 0; i < 16; ++i) {
            int lr = lbase + i;
            float acc = bv;
            acc = fmaf(in[lr + 0][dnl], w0, acc);
            acc = fmaf(in[lr + 1][dnl], w1, acc);
            acc = fmaf(in[lr + 2][dnl], w2, acc);
            acc = fmaf(in[lr + 3][dnl], w3, acc);
            res[lr][dnl] = siluf(acc);
        }
    }
    __syncthreads();
    {
        int dnl = col, lbase = (tid >> 6) * 16;
#pragma unroll
        for (int i = 0; i < 16; ++i) {
            int lr = lbase + i;
            xin[((size_t)(b * LL + l0 + lr)) * DN + dn0 + dnl] = res[lr][dnl];
        }
    }
    {
        int ll = col, dbase = (tid >> 6) * 16;
#pragma unroll
        for (int i = 0; i < 16; ++i) {
            int dnl = dbase + i;
            xinT[((size_t)(b * DN + dn0 + dnl)) * LL + l0 + ll] = res[ll][dnl];
        }
    }
}

// ---------------- scan v3: wave-per-channel, 16 states in registers ----------------
// Block = 256 threads = 4 waves; each wave owns one (b,dn) channel.
// Lane = one chunk of SCHUNK=32 time-steps, holding all 16 h-states in VGPRs.
// Chunk stitching: Hillis-Steele shfl_up scan of (a,h) pairs across 64 lanes.
// Gate fused: y = (sum_n h*C + Dp*u) * silu(z), bf16 time-major out.
__global__ __launch_bounds__(256)
void scan_kernel(const float* __restrict__ dtT,   // [B,DN,L]
                 const float* __restrict__ xdbl,  // [B,L,80]
                 const float* __restrict__ uT,    // [B,DN,L]
                 const float* __restrict__ zT,    // [B,DN,L]
                 const float* __restrict__ A_log, // [DN,16]
                 const float* __restrict__ Dp,    // [DN]
                 __hip_bfloat16* __restrict__ ygT)// [B,DN,L]
{
    int wave = threadIdx.x >> 6;
    int lane = threadIdx.x & 63;
    int c = blockIdx.x * 4 + wave;   // channel 0..B*DN-1
    int b = c / DN;
    int dn = c % DN;

    // A2[n] = A_n * log2(e), so dA = exp2(dtv * A2[n])
    float A2[NS];
#pragma unroll
    for (int q = 0; q < 4; ++q) {
        float4 al = *reinterpret_cast<const float4*>(&A_log[dn * NS + q * 4]);
        A2[q * 4 + 0] = -expf(al.x) * LOG2E;
        A2[q * 4 + 1] = -expf(al.y) * LOG2E;
        A2[q * 4 + 2] = -expf(al.z) * LOG2E;
        A2[q * 4 + 3] = -expf(al.w) * LOG2E;
    }
    float Dpv = Dp[dn];

    const size_t baseT = ((size_t)b * DN + dn) * LL;
    const int t0 = lane * SCHUNK;
    const float* dt_p = dtT + baseT + t0;
    const float* u_p  = uT  + baseT + t0;
    const float* z_p  = zT  + baseT + t0;
    const float* BC_p = xdbl + ((size_t)b * LL + t0) * 80 + DTR;  // B at +0, C at +16

    // ---- Phase 1: local scan from zero state; sum dt for chunk decay ----
    float h[NS];
#pragma unroll
    for (int n = 0; n < NS; ++n) h[n] = 0.f;
    float sdt = 0.f;

    for (int t4 = 0; t4 < SCHUNK; t4 += 4) {
        float4 dtv4 = *reinterpret_cast<const float4*>(dt_p + t4);
        float4 u4   = *reinterpret_cast<const float4*>(u_p + t4);
        const float* dv = &dtv4.x;
        const float* uv = &u4.x;
#pragma unroll
        for (int j = 0; j < 4; ++j) {
            float dtv = dv[j], u = uv[j];
            float dtu = dtv * u;
            const float* Brow = BC_p + (size_t)(t4 + j) * 80;
            float Bv[NS];
#pragma unroll
            for (int q = 0; q < 4; ++q)
                *reinterpret_cast<float4*>(&Bv[q * 4]) =
                    *reinterpret_cast<const float4*>(&Brow[q * 4]);
#pragma unroll
            for (int n = 0; n < NS; ++n) {
                float dA = exp2f(dtv * A2[n]);
                h[n] = fmaf(h[n], dA, dtu * Bv[n]);
            }
            sdt += dtv;
        }
    }
    // chunk decay a[n] = prod dA = exp2(A2[n] * sum dt)
    float a[NS];
#pragma unroll
    for (int n = 0; n < NS; ++n) a[n] = exp2f(A2[n] * sdt);

    // ---- Phase 2: wave-wide scan of segment maps (a,h); f(x) = a*x + h ----
    // compose(earlier E, later L)(x) = aL*aE*x + aL*hE + hL
#pragma unroll
    for (int d = 1; d < 64; d <<= 1) {
#pragma unroll
        for (int n = 0; n < NS; ++n) {
            float pa = __shfl_up(a[n], d, 64);
            float ph = __shfl_up(h[n], d, 64);
            if (lane >= d) {
                h[n] = fmaf(ph, a[n], h[n]);
                a[n] = a[n] * pa;
            }
        }
    }
    // exclusive prefix: entry state H0 = inclusive prefix of lane-1
#pragma unroll
    for (int n = 0; n < NS; ++n) {
        float ph = __shfl_up(h[n], 1, 64);
        h[n] = (lane == 0) ? 0.f : ph;   // reuse h as running state
    }

    // ---- Phase 3: re-scan from H0, gate, emit bf16 (paired u32 stores) ----
    unsigned short prev = 0;
    unsigned short* y_p = (unsigned short*)(ygT + baseT + t0);
    for (int t4 = 0; t4 < SCHUNK; t4 += 4) {
        float4 dtv4 = *reinterpret_cast<const float4*>(dt_p + t4);
        float4 u4   = *reinterpret_cast<const float4*>(u_p + t4);
        float4 z4   = *reinterpret_cast<const float4*>(z_p + t4);
        const float* dv = &dtv4.x;
        const float* uv = &u4.x;
        const float* zv = &z4.x;
#pragma unroll
        for (int j = 0; j < 4; ++j) {
            float dtv = dv[j], u = uv[j], z = zv[j];
            float dtu = dtv * u;
            const float* Brow = BC_p + (size_t)(t4 + j) * 80;
            float Bv[NS], Cv[NS];
#pragma unroll
            for (int q = 0; q < 4; ++q) {
                *reinterpret_cast<float4*>(&Bv[q * 4]) =
                    *reinterpret_cast<const float4*>(&Brow[q * 4]);
                *reinterpret_cast<float4*>(&Cv[q * 4]) =
                    *reinterpret_cast<const float4*>(&Brow[NS + q * 4]);
            }
            float p = 0.f;
#pragma unroll
            for (int n = 0; n < NS; ++n) {
                float dA = exp2f(dtv * A2[n]);
                h[n] = fmaf(h[n], dA, dtu * Bv[n]);
                p = fmaf(h[n], Cv[n], p);
            }
            float val = fmaf(Dpv, u, p) * siluf(z);
            unsigned short vb = __builtin_bit_cast(unsigned short, __float2bfloat16(val));
            if ((j & 1) == 0) {
                prev = vb;
            } else {
                unsigned pk = (unsigned)prev | ((unsigned)vb << 16);
                *reinterpret_cast<unsigned*>(&y_p[t4 + j - 1]) = pk;
            }
        }
    }
}

// ---------------- bf16 transpose: ygT [B,DN,L] -> yg [M,DN] ----------------
__global__ void transpose_yg_kernel(const __hip_bfloat16* __restrict__ ygT,
                                    __hip_bfloat16* __restrict__ yg)
{
    __shared__ unsigned short t[64][65];
    int dn0 = blockIdx.x * 64, l0 = blockIdx.y * 64, b = blockIdx.z;
    int col = threadIdx.x & 63;
    const unsigned short* src = (const unsigned short*)ygT;
    unsigned short* dst = (unsigned short*)yg;
    for (int r = threadIdx.x >> 6; r < 64; r += 4)
        t[r][col] = src[((size_t)(b * DN + dn0 + r)) * LL + l0 + col];
    __syncthreads();
    for (int r = threadIdx.x >> 6; r < 64; r += 4)
        dst[((size_t)(b * LL + l0 + r)) * DN + dn0 + col] = t[col][r];
}

extern "C" void kernel_launch(void* const* d_in, const int* in_sizes, int n_in,
                              void* d_out, int out_size, void* d_ws, size_t ws_size,
                              hipStream_t stream) {
    const float* x         = (const float*)d_in[0];
    const float* gamma     = (const float*)d_in[1];
    const float* beta      = (const float*)d_in[2];
    const float* ln_g      = (const float*)d_in[3];
    const float* ln_b      = (const float*)d_in[4];
    const float* in_proj_w = (const float*)d_in[5];
    const float* conv_w    = (const float*)d_in[6];
    const float* conv_b    = (const float*)d_in[7];
    const float* x_proj_w  = (const float*)d_in[8];
    const float* dt_proj_w = (const float*)d_in[9];
    const float* dt_proj_b = (const float*)d_in[10];
    const float* A_log     = (const float*)d_in[11];
    const float* Dp        = (const float*)d_in[12];
    const float* out_proj_w= (const float*)d_in[13];
    float* out = (float*)d_out;

    char* ws = (char*)d_ws;
    float* xz    = (float*)(ws);                        // 50,331,648 B [0, 50.3M)
    float* xin   = (float*)(ws + 50331648);             // 25,165,824 B
    float* xinT  = (float*)(ws + 75497472);             // 25,165,824 B
    float* xdbl  = (float*)(ws + 100663296);            //  1,310,720 B
    float* zT    = (float*)(ws + 101974016);            // 25,165,824 B
    __hip_bfloat16* xn_bf = (__hip_bfloat16*)(ws + 127139840);  // 6,291,456 B
    __hip_bfloat16* w1_bf = (__hip_bfloat16*)(ws + 133431296);  // 4,718,592 B -> 138,149,888
    // aliases into xz (dead after conv):
    float* dtT = (float*)(ws);                          // 25,165,824 B
    __hip_bfloat16* ygT = (__hip_bfloat16*)(ws + 25165824);   // 12,582,912 B
    __hip_bfloat16* yg  = (__hip_bfloat16*)(ws + 37748736);   // 12,582,912 B
    // alias into xn_bf/w1_bf (dead after in_proj GEMM): split-K partials 10.5 MB
    float* xp_part = (float*)(ws + 127139840);          // 10,485,760 B <= 11,010,048 B
    // alias into xn_bf (dead after partials reduced): out_proj bf16 weights
    __hip_bfloat16* w2_bf = xn_bf;                      // 2,359,296 B

    // 1. LN + FiLM -> bf16
    ln_film_kernel<<<MM, 256, 0, stream>>>(x, gamma, beta, ln_g, ln_b, xn_bf);

    // 1b. cast in_proj_w -> bf16
    cast_bf16_kernel<<<(2 * DN * DD / 4 + 255) / 256, 256, 0, stream>>>(in_proj_w, w1_bf, 2 * DN * DD);

    // 2. xz = xn @ in_proj_w^T   [4096 x 3072], K=768  (bf16 MFMA)
    gemm_mfma_kernel<0><<<dim3(3072 / 128, MM / 128), 256, 0, stream>>>(
        xn_bf, DD, w1_bf, DD, xz, 2 * DN, DD, nullptr);

    // 2b. transpose z-half -> zT [B,DN,L]
    transpose_z_kernel<<<dim3(LL / 64, DN / 64, BB), 256, 0, stream>>>(xz, zT);

    // 3. tiled conv + silu -> xin (normal) + xinT (time-major); xz dead after
    conv_silu_tile_kernel<<<dim3(LL / 64, DN / 64, BB), 256, 0, stream>>>(
        xz, conv_w, conv_b, xin, xinT);

    // 4a. x_dbl = xin @ x_proj_w^T   [4096 x 80]  (f32, split-K 8)
    gemm_xproj_splitk<<<dim3(2, MM / 64, KSPLIT), 256, 0, stream>>>(
        xin, x_proj_w, xp_part);
    reduce_xproj_kernel<<<(MM * 80 / 4 + 255) / 256, 256, 0, stream>>>(xp_part, xdbl);

    // 4b. dtT = softplus(x_dbl[:, :48] @ dt_proj_w^T + b), stored [B,DN,L]
    gemm_tn_kernel<3><<<dim3(DN / 64, MM / 64), 256, 0, stream>>>(
        xdbl, 80, dt_proj_w, dtT, 0, MM, DN, DTR, dt_proj_b);

    // 5. scan v3 (wave-per-channel) + fused gate -> ygT (bf16, time-major)
    scan_kernel<<<BB * DN / 4, 256, 0, stream>>>(dtT, xdbl, xinT, zT, A_log, Dp, ygT);

    // 5b. transpose ygT -> yg [M,DN]
    transpose_yg_kernel<<<dim3(DN / 64, LL / 64, BB), 256, 0, stream>>>(ygT, yg);

    // 6-pre. cast out_proj_w -> bf16
    cast_bf16_kernel<<<(DD * DN / 4 + 255) / 256, 256, 0, stream>>>(out_proj_w, w2_bf, DD * DN);

    // 6. out = x + yg @ out_proj_w^T   [4096 x 768], K=1536  (bf16 MFMA)
    gemm_mfma_kernel<2><<<dim3(DD / 128, MM / 128), 256, 0, stream>>>(
        yg, DN, w2_bf, DN, out, DD, DN, x);
}